// Round 16
// baseline (179.106 us; speedup 1.0000x reference)
//
#include <hip/hip_runtime.h>
#include <hip/hip_bf16.h>
#include <stdint.h>

#define B_ 2
#define S_ 2048
#define D_ 1024
#define H_ 16
#define DH 64

typedef __attribute__((ext_vector_type(4))) float f32x4;
typedef __attribute__((ext_vector_type(8))) short s16x8;
typedef __attribute__((ext_vector_type(4))) short s16x4;

__device__ inline short f2bf(float f) {
  union { float f; unsigned u; } v; v.f = f;
  unsigned r = (v.u + 0x7fffu + ((v.u >> 16) & 1u)) >> 16;
  return (short)r;
}

__device__ inline float bfbits_lo(unsigned u) {
  union { unsigned x; float f; } v; v.x = u << 16; return v.f;
}
__device__ inline float bfbits_hi(unsigned u) {
  union { unsigned x; float f; } v; v.x = u & 0xffff0000u; return v.f;
}

__device__ inline float exp2v(float x) {
  float r; asm("v_exp_f32 %0, %1" : "=v"(r) : "v"(x)); return r;
}
__device__ inline unsigned cvtpk(float a, float b) {
  unsigned r; asm("v_cvt_pk_bf16_f32 %0, %1, %2" : "=v"(r) : "v"(a), "v"(b));
  return r;
}

// 4 weight matrices: out[n][k] = (bf16) in[k][n], D_ x D_ (blockIdx.z selects)
__global__ __launch_bounds__(256) void transpose_cvt4(
    const float* __restrict__ i0, const float* __restrict__ i1,
    const float* __restrict__ i2, const float* __restrict__ i3,
    short* o0, short* o1, short* o2, short* o3) {
  int z = blockIdx.z;
  const float* in = z == 0 ? i0 : (z == 1 ? i1 : (z == 2 ? i2 : i3));
  short* out = z == 0 ? o0 : (z == 1 ? o1 : (z == 2 ? o2 : o3));
  __shared__ float tile[32][33];
  int bx = blockIdx.x, by = blockIdx.y;
  int x = bx * 32 + threadIdx.x;
#pragma unroll
  for (int i = 0; i < 32; i += 8) {
    int y = by * 32 + threadIdx.y + i;
    tile[threadIdx.y + i][threadIdx.x] = in[(size_t)y * D_ + x];
  }
  __syncthreads();
  int ox = by * 32 + threadIdx.x;
#pragma unroll
  for (int i = 0; i < 32; i += 8) {
    int oy = bx * 32 + threadIdx.y + i;
    out[(size_t)oy * D_ + ox] = f2bf(tile[threadIdx.x][threadIdx.y + i]);
  }
}

__device__ inline void gload_lds16(const void* g, void* l) {
  __builtin_amdgcn_global_load_lds(
      (const __attribute__((address_space(1))) unsigned*)g,
      (__attribute__((address_space(3))) unsigned*)l, 16, 0, 0);
}

#define BM 128
#define BN 128
#define BK 32

// Triple GEMM (f32 A, converted in-register) + fused mgp slice (z==3).
// z==2 writes its result TRANSPOSED as vt(B,H,DH,S) bf16.
// blockIdx.x XCD-swizzled (256 blocks, 8 XCDs) for L2 locality.
__global__ __launch_bounds__(256) void gemm_qkv(
    const float* __restrict__ A0, const float* __restrict__ A1, const float* __restrict__ A2,
    const short* __restrict__ Bt0, const short* __restrict__ Bt1, const short* __restrict__ Bt2,
    const float* __restrict__ bs0, const float* __restrict__ bs1, const float* __restrict__ bs2,
    short* __restrict__ Cq, short* __restrict__ Ck, short* __restrict__ vtout,
    const int* __restrict__ mask, const float* __restrict__ gp,
    short* __restrict__ mgpout, int nmg,
    int M, int N, int K, float os0) {
  int z = blockIdx.y;
  if (z == 3) {  // fused mask*gp compression, grid-stride
    int i = (blockIdx.x * 256 + threadIdx.x) * 4;
    int stride = gridDim.x * 256 * 4;
    for (; i < nmg; i += stride) {
      int4 m = *(const int4*)(mask + i);
      float4 g = *(const float4*)(gp + i);
      short b0 = f2bf(g.x); if (!b0) b0 = (short)0x0080;
      short b1 = f2bf(g.y); if (!b1) b1 = (short)0x0080;
      short b2 = f2bf(g.z); if (!b2) b2 = (short)0x0080;
      short b3 = f2bf(g.w); if (!b3) b3 = (short)0x0080;
      s16x4 o;
      o.x = m.x ? b0 : 0;
      o.y = m.y ? b1 : 0;
      o.z = m.z ? b2 : 0;
      o.w = m.w ? b3 : 0;
      *(s16x4*)(mgpout + i) = o;
    }
    return;
  }
  const float* A = z == 0 ? A0 : (z == 1 ? A1 : A2);
  const short* Bt = z == 0 ? Bt0 : (z == 1 ? Bt1 : Bt2);
  const float* bias = z == 0 ? bs0 : (z == 1 ? bs1 : bs2);
  float oscale = z == 0 ? os0 : 1.0f;

  __shared__ __align__(16) float As[BM * BK];   // f32, granule-swizzled
  __shared__ __align__(16) short Bs[BN * BK];
  int tid = threadIdx.x;
  int lane = tid & 63, wave = tid >> 6;
  int l15 = lane & 15, l4 = lane >> 4;
  int ntn = N / BN;
  int bid = blockIdx.x;
  bid = ((bid & 7) << 5) | (bid >> 3);  // bijective: nwg=256, 256%8==0
  int bm = bid / ntn, bn = bid % ntn;
  int row0 = bm * BM, col0 = bn * BN;
  int wm = (wave >> 1) * 64, wn = (wave & 1) * 64;
  int q7 = l15 & 7;

  f32x4 acc[4][4] = {};

  for (int k0 = 0; k0 < K; k0 += BK) {
    __syncthreads();
    // B: bf16 tile, 512 x 16B chunks, linear (proven path, unchanged)
#pragma unroll
    for (int it = 0; it < 2; ++it) {
      int ch = it * 256 + tid;
      int r = ch >> 2, c = (ch & 3) * 8;
      int ldsbase = (it * 256 + wave * 64) * 8;  // shorts
      gload_lds16(Bt + (size_t)(col0 + r) * K + k0 + c, &Bs[ldsbase]);
    }
    // A: f32 tile, 1024 x 16B chunks (4 floats); source pre-swizzled so
    // LDS phys granule p of row r holds source granule p ^ (r&7)
#pragma unroll
    for (int it = 0; it < 4; ++it) {
      int ch = it * 256 + tid;
      int r = ch >> 3, g = (ch & 7) ^ (r & 7);
      int ldsbase = (it * 256 + wave * 64) * 4;  // floats
      gload_lds16(A + (size_t)(row0 + r) * K + k0 + g * 4, &As[ldsbase]);
    }
    __syncthreads();
    s16x8 af[4], bf[4];
#pragma unroll
    for (int mf = 0; mf < 4; ++mf) {
      int row = wm + mf * 16 + l15;  // row&7 == l15&7 == q7
      f32x4 a0 = *(const f32x4*)&As[row * BK + (((2 * l4) ^ q7) * 4)];
      f32x4 a1 = *(const f32x4*)&As[row * BK + (((2 * l4 + 1) ^ q7) * 4)];
      union { unsigned w[4]; s16x8 v; } u;
      u.w[0] = cvtpk(a0[0], a0[1]);
      u.w[1] = cvtpk(a0[2], a0[3]);
      u.w[2] = cvtpk(a1[0], a1[1]);
      u.w[3] = cvtpk(a1[2], a1[3]);
      af[mf] = u.v;
    }
#pragma unroll
    for (int nf = 0; nf < 4; ++nf)
      bf[nf] = *(const s16x8*)&Bs[(wn + nf * 16 + l15) * BK + l4 * 8];
#pragma unroll
    for (int mf = 0; mf < 4; ++mf)
#pragma unroll
      for (int nf = 0; nf < 4; ++nf)
        acc[mf][nf] = __builtin_amdgcn_mfma_f32_16x16x32_bf16(af[mf], bf[nf],
                                                              acc[mf][nf], 0, 0, 0);
  }

  if (z == 2) {
    // transposed bf16 write: vt[((b*H+h)*DH + dh)*S + s]
    int b = row0 >> 11;                 // S_ = 2048
    int h = (col0 + wn) >> 6;           // col0+wn multiple of 64
    int sbase = (row0 & (S_ - 1)) + wm + l4 * 4;
    short* vtb = vtout + ((size_t)(b * H_ + h) * DH) * S_;
#pragma unroll
    for (int nf = 0; nf < 4; ++nf) {
      int dh = nf * 16 + l15;
      float bv = bias[col0 + wn + dh];
#pragma unroll
      for (int mf = 0; mf < 4; ++mf) {
        uint2 o;
        o.x = cvtpk(acc[mf][nf][0] + bv, acc[mf][nf][1] + bv);
        o.y = cvtpk(acc[mf][nf][2] + bv, acc[mf][nf][3] + bv);
        *(uint2*)&vtb[(size_t)dh * S_ + sbase + mf * 16] = o;
      }
    }
    return;
  }

  short* C = z == 0 ? Cq : Ck;
#pragma unroll
  for (int nf = 0; nf < 4; ++nf) {
    int gcol = col0 + wn + nf * 16 + l15;
    float bv = bias[gcol];
#pragma unroll
    for (int mf = 0; mf < 4; ++mf) {
#pragma unroll
      for (int r = 0; r < 4; ++r) {
        int grow = row0 + wm + mf * 16 + l4 * 4 + r;
        C[(size_t)grow * N + gcol] = f2bf((acc[mf][nf][r] + bv) * oscale);
      }
    }
  }
}

// Final projection: bf16 A (ctx) x bf16 Bt + bias -> f32 out. Proven path.
__global__ __launch_bounds__(256) void gemm_out(
    const short* __restrict__ A, const short* __restrict__ Bt,
    const float* __restrict__ bias, float* __restrict__ C,
    int M, int N, int K) {
  __shared__ __align__(16) short As[BM * BK];
  __shared__ __align__(16) short Bs[BN * BK];
  int tid = threadIdx.x;
  int lane = tid & 63, wave = tid >> 6;
  int l15 = lane & 15, l4 = lane >> 4;
  int ntn = N / BN;
  int bid = blockIdx.x;
  bid = ((bid & 7) << 5) | (bid >> 3);
  int bm = bid / ntn, bn = bid % ntn;
  int row0 = bm * BM, col0 = bn * BN;
  int wm = (wave >> 1) * 64, wn = (wave & 1) * 64;

  f32x4 acc[4][4] = {};

  for (int k0 = 0; k0 < K; k0 += BK) {
    __syncthreads();
#pragma unroll
    for (int it = 0; it < 2; ++it) {
      int ch = it * 256 + tid;
      int r = ch >> 2, c = (ch & 3) * 8;
      int ldsbase = (it * 256 + wave * 64) * 8;
      gload_lds16(A + (size_t)(row0 + r) * K + k0 + c, &As[ldsbase]);
      gload_lds16(Bt + (size_t)(col0 + r) * K + k0 + c, &Bs[ldsbase]);
    }
    __syncthreads();
    s16x8 af[4], bf[4];
#pragma unroll
    for (int mf = 0; mf < 4; ++mf)
      af[mf] = *(const s16x8*)&As[(wm + mf * 16 + l15) * BK + l4 * 8];
#pragma unroll
    for (int nf = 0; nf < 4; ++nf)
      bf[nf] = *(const s16x8*)&Bs[(wn + nf * 16 + l15) * BK + l4 * 8];
#pragma unroll
    for (int mf = 0; mf < 4; ++mf)
#pragma unroll
      for (int nf = 0; nf < 4; ++nf)
        acc[mf][nf] = __builtin_amdgcn_mfma_f32_16x16x32_bf16(af[mf], bf[nf],
                                                              acc[mf][nf], 0, 0, 0);
  }

#pragma unroll
  for (int nf = 0; nf < 4; ++nf) {
    int gcol = col0 + wn + nf * 16 + l15;
    float bv = bias[gcol];
#pragma unroll
    for (int mf = 0; mf < 4; ++mf) {
#pragma unroll
      for (int r = 0; r < 4; ++r) {
        int grow = row0 + wm + mf * 16 + l4 * 4 + r;
        C[(size_t)grow * N + gcol] = acc[mf][nf][r] + bv;
      }
    }
  }
}

#define QB 128
#define NB 64
#define NTILES (S_ / NB)
#define M0_SHIFT 12.0f

// Banked 85us attention (byte-identical to r14's).
__global__ __launch_bounds__(256, 3) void attn_fused(const short* __restrict__ Qp,
                                                     const short* __restrict__ Kp,
                                                     const short* __restrict__ VT,
                                                     const short* __restrict__ MGP,
                                                     short* __restrict__ ctx) {
  __shared__ __align__(16) short Ks[2][64 * 64];
  __shared__ __align__(16) short Vs[2][64 * 64];
  __shared__ __align__(16) short Ps[4][32 * 64];  // wave-private P

  int tid = threadIdx.x, lane = tid & 63, wave = tid >> 6;
  int l15 = lane & 15, l4 = lane >> 4;
  int q0 = blockIdx.x * QB;
  int bh = blockIdx.y;
  int b = bh >> 4, h = bh & 15;
  int wq = wave * 32;

  const short* Qbase = Qp + (size_t)b * S_ * D_ + (size_t)h * DH;
  const short* Kbase = Kp + (size_t)b * S_ * D_ + (size_t)h * DH;
  const short* Vbase = VT + (size_t)(b * H_ + h) * DH * S_;  // rows d, stride S_
  const short* Mrow0 = MGP + (size_t)b * S_ * S_ + (size_t)(q0 + wq + l15) * S_ + l4 * 4;
  const short* Mrow1 = Mrow0 + (size_t)16 * S_;

  int i0 = tid, i1 = 256 + tid;
  int r0 = i0 >> 3, c0 = (i0 & 7) ^ (r0 & 7);
  int r1 = i1 >> 3, c1 = (i1 & 7) ^ (r1 & 7);
  int ldsA = wave * 512;
  int ldsB = 2048 + wave * 512;

#define STAGE(kv0, buf)                                                       \
  do {                                                                        \
    gload_lds16(Kbase + (size_t)((kv0) + r0) * D_ + c0 * 8, &Ks[buf][ldsA]);  \
    gload_lds16(Kbase + (size_t)((kv0) + r1) * D_ + c1 * 8, &Ks[buf][ldsB]);  \
    gload_lds16(Vbase + (size_t)r0 * S_ + (kv0) + c0 * 8, &Vs[buf][ldsA]);    \
    gload_lds16(Vbase + (size_t)r1 * S_ + (kv0) + c1 * 8, &Vs[buf][ldsB]);    \
  } while (0)

  s16x8 qf[2][2];
#pragma unroll
  for (int mf = 0; mf < 2; ++mf)
#pragma unroll
    for (int ks = 0; ks < 2; ++ks)
      qf[mf][ks] = *(const s16x8*)(Qbase + (size_t)(q0 + wq + mf * 16 + l15) * D_ +
                                   ks * 32 + l4 * 8);

  float lsum[2] = {0.f, 0.f};
  f32x4 oacc[2][4] = {};

  STAGE(0, 0);

  int q7 = l15 & 7;
  short* Pw = &Ps[wave][0];
  int prow[2] = {l15 * 64, (16 + l15) * 64};

  for (int t = 0; t < NTILES; ++t) {
    int buf = t & 1;
    int kvt = t * NB;

    uint2 g2[2][4];
#pragma unroll
    for (int nf = 0; nf < 4; ++nf) {
      g2[0][nf] = *(const uint2*)(Mrow0 + kvt + nf * 16);
      g2[1][nf] = *(const uint2*)(Mrow1 + kvt + nf * 16);
    }
    __builtin_amdgcn_sched_barrier(0);
    if (t + 1 < NTILES) {
      STAGE((t + 1) * NB, buf ^ 1);
      __builtin_amdgcn_sched_barrier(0);
      asm volatile("s_waitcnt vmcnt(12)" ::: "memory");
    } else {
      __builtin_amdgcn_sched_barrier(0);
      asm volatile("s_waitcnt vmcnt(8)" ::: "memory");
    }
    __builtin_amdgcn_s_barrier();
    __builtin_amdgcn_sched_barrier(0);

    f32x4 sacc[2][4] = {};
    __builtin_amdgcn_s_setprio(1);
#pragma unroll
    for (int nf = 0; nf < 4; ++nf) {
      int R = nf * 16 + l15;
#pragma unroll
      for (int ks = 0; ks < 2; ++ks) {
        s16x8 kf = *(const s16x8*)&Ks[buf][R * 64 + (((ks * 4 + l4) ^ q7) * 8)];
#pragma unroll
        for (int mf = 0; mf < 2; ++mf)
          sacc[mf][nf] = __builtin_amdgcn_mfma_f32_16x16x32_bf16(kf, qf[mf][ks],
                                                                 sacc[mf][nf], 0, 0, 0);
      }
    }
    __builtin_amdgcn_s_setprio(0);

    float ee[2][4][4];
#pragma unroll
    for (int mf = 0; mf < 2; ++mf)
#pragma unroll
      for (int nf = 0; nf < 4; ++nf)
#pragma unroll
        for (int r = 0; r < 4; ++r)
          ee[mf][nf][r] = exp2v(sacc[mf][nf][r] - M0_SHIFT);

    if (t + 1 < NTILES)
      asm volatile("s_waitcnt vmcnt(4)" ::: "memory");
    else
      asm volatile("s_waitcnt vmcnt(0)" ::: "memory");
    __builtin_amdgcn_sched_barrier(0);

#pragma unroll
    for (int mf = 0; mf < 2; ++mf) {
#pragma unroll
      for (int nf = 0; nf < 4; ++nf) {
        float gv0 = bfbits_lo(g2[mf][nf].x), gv1 = bfbits_hi(g2[mf][nf].x);
        float gv2 = bfbits_lo(g2[mf][nf].y), gv3 = bfbits_hi(g2[mf][nf].y);
        float e0 = ee[mf][nf][0], e1 = ee[mf][nf][1];
        float e2 = ee[mf][nf][2], e3 = ee[mf][nf][3];
        lsum[mf] += (gv0 != 0.f) ? e0 : 0.f;
        lsum[mf] += (gv1 != 0.f) ? e1 : 0.f;
        lsum[mf] += (gv2 != 0.f) ? e2 : 0.f;
        lsum[mf] += (gv3 != 0.f) ? e3 : 0.f;
        uint2 wp;
        wp.x = cvtpk(e0 * gv0, e1 * gv1);
        wp.y = cvtpk(e2 * gv2, e3 * gv3);
        int gr = ((nf * 2 + (l4 >> 1)) ^ q7) * 8 + (l4 & 1) * 4;
        *(uint2*)&Pw[prow[mf] + gr] = wp;
      }
    }

    __builtin_amdgcn_s_setprio(1);
#pragma unroll
    for (int ks = 0; ks < 2; ++ks) {
      s16x8 pa[2];
#pragma unroll
      for (int mf = 0; mf < 2; ++mf)
        pa[mf] = *(const s16x8*)&Pw[prow[mf] + (((ks * 4 + l4) ^ q7) * 8)];
#pragma unroll
      for (int df = 0; df < 4; ++df) {
        s16x8 vf = *(const s16x8*)&Vs[buf][(df * 16 + l15) * 64 +
                                           (((ks * 4 + l4) ^ q7) * 8)];
#pragma unroll
        for (int mf = 0; mf < 2; ++mf)
          oacc[mf][df] = __builtin_amdgcn_mfma_f32_16x16x32_bf16(vf, pa[mf],
                                                                 oacc[mf][df], 0, 0, 0);
      }
    }
    __builtin_amdgcn_s_setprio(0);

    asm volatile("s_waitcnt lgkmcnt(0)" ::: "memory");
    __builtin_amdgcn_s_barrier();
  }
#undef STAGE

#pragma unroll
  for (int mf = 0; mf < 2; ++mf) {
    float ls = lsum[mf];
    ls += __shfl_xor(ls, 16);
    ls += __shfl_xor(ls, 32);
    float inv = 1.f / ls;
    short* crow = ctx + ((size_t)(b * S_ + q0 + wq + mf * 16 + l15)) * D_ + h * DH;
#pragma unroll
    for (int df = 0; df < 4; ++df) {
      uint2 o;
      o.x = cvtpk(oacc[mf][df][0] * inv, oacc[mf][df][1] * inv);
      o.y = cvtpk(oacc[mf][df][2] * inv, oacc[mf][df][3] * inv);
      *(uint2*)(crow + df * 16 + l4 * 4) = o;
    }
  }
}

extern "C" void kernel_launch(void* const* d_in, const int* in_sizes, int n_in,
                              void* d_out, int out_size, void* d_ws, size_t ws_size,
                              hipStream_t stream) {
  const float* query = (const float*)d_in[0];
  const float* key_in = (const float*)d_in[1];
  const float* value = (const float*)d_in[2];
  const float* group_prob = (const float*)d_in[3];
  const int* mask = (const int*)d_in[4];
  const float* wq_k = (const float*)d_in[5];
  const float* wq_b = (const float*)d_in[6];
  const float* wk_k = (const float*)d_in[7];
  const float* wk_b = (const float*)d_in[8];
  const float* wv_k = (const float*)d_in[9];
  const float* wv_b = (const float*)d_in[10];
  const float* wo_k = (const float*)d_in[11];
  const float* wo_b = (const float*)d_in[12];
  float* out = (float*)d_out;

  short* ws = (short*)d_ws;
  const size_t NT = (size_t)B_ * S_ * D_;  // 4.19M elems
  short* wqt = ws;
  short* wkt = wqt + (size_t)D_ * D_;
  short* wvt = wkt + (size_t)D_ * D_;
  short* wot = wvt + (size_t)D_ * D_;
  short* qp = wot + (size_t)D_ * D_;
  short* kp = qp + NT;
  short* vt = kp + NT;   // V projection written directly transposed (B,H,DH,S)
  short* ctx = vt + NT;
  short* mgp = ctx + NT; // dedicated region; total ws use = 58.3 MB

  dim3 tb(32, 8);
  transpose_cvt4<<<dim3(D_ / 32, D_ / 32, 4), tb, 0, stream>>>(
      wq_k, wk_k, wv_k, wo_k, wqt, wkt, wvt, wot);

  int M = B_ * S_;
  int gblocks = (M / BM) * (D_ / BN);
  int nmg = B_ * S_ * S_;
  const float QSCALE = 0.125f * 1.4426950408889634f;  // 1/sqrt(dh) * log2(e)
  // z=0..2: Q/K/V projections reading f32 activations directly;
  // z=2 writes transposed into vt; z=3: mgp fusion hidden under GEMM compute
  gemm_qkv<<<dim3(gblocks, 4), 256, 0, stream>>>(
      query, key_in, value, wqt, wkt, wvt, wq_b, wk_b, wv_b,
      qp, kp, vt, mask, group_prob, mgp, nmg, M, D_, D_, QSCALE);

  dim3 ag(S_ / QB, B_ * H_);
  attn_fused<<<ag, 256, 0, stream>>>(qp, kp, vt, mgp, ctx);

  gemm_out<<<gblocks, 256, 0, stream>>>(ctx, wot, wo_b, out, M, D_, D_);
}

// Round 17
// 175.202 us; speedup vs baseline: 1.0223x; 1.0223x over previous
//
#include <hip/hip_runtime.h>
#include <hip/hip_bf16.h>
#include <stdint.h>

#define B_ 2
#define S_ 2048
#define D_ 1024
#define H_ 16
#define DH 64

typedef __attribute__((ext_vector_type(4))) float f32x4;
typedef __attribute__((ext_vector_type(8))) short s16x8;
typedef __attribute__((ext_vector_type(4))) short s16x4;

__device__ inline short f2bf(float f) {
  union { float f; unsigned u; } v; v.f = f;
  unsigned r = (v.u + 0x7fffu + ((v.u >> 16) & 1u)) >> 16;
  return (short)r;
}

__device__ inline float bfbits_lo(unsigned u) {
  union { unsigned x; float f; } v; v.x = u << 16; return v.f;
}
__device__ inline float bfbits_hi(unsigned u) {
  union { unsigned x; float f; } v; v.x = u & 0xffff0000u; return v.f;
}

__device__ inline float exp2v(float x) {
  float r; asm("v_exp_f32 %0, %1" : "=v"(r) : "v"(x)); return r;
}
__device__ inline unsigned cvtpk(float a, float b) {
  unsigned r; asm("v_cvt_pk_bf16_f32 %0, %1, %2" : "=v"(r) : "v"(a), "v"(b));
  return r;
}

// 3 tensors f32->bf16 in one launch (blockIdx.y selects)
__global__ __launch_bounds__(256) void cvt3_f32_bf16(const float* __restrict__ a,
                                                     const float* __restrict__ b,
                                                     const float* __restrict__ c,
                                                     short* oa, short* ob, short* oc,
                                                     int n) {
  int z = blockIdx.y;
  const float* in = z == 0 ? a : (z == 1 ? b : c);
  short* out = z == 0 ? oa : (z == 1 ? ob : oc);
  int i = (blockIdx.x * 256 + threadIdx.x) * 4;
  if (i < n) {
    float4 v = *(const float4*)(in + i);
    s16x4 o;
    o.x = f2bf(v.x); o.y = f2bf(v.y); o.z = f2bf(v.z); o.w = f2bf(v.w);
    *(s16x4*)(out + i) = o;
  }
}

// 4 weight matrices: out[n][k] = (bf16) in[k][n], D_ x D_ (blockIdx.z selects)
__global__ __launch_bounds__(256) void transpose_cvt4(
    const float* __restrict__ i0, const float* __restrict__ i1,
    const float* __restrict__ i2, const float* __restrict__ i3,
    short* o0, short* o1, short* o2, short* o3) {
  int z = blockIdx.z;
  const float* in = z == 0 ? i0 : (z == 1 ? i1 : (z == 2 ? i2 : i3));
  short* out = z == 0 ? o0 : (z == 1 ? o1 : (z == 2 ? o2 : o3));
  __shared__ float tile[32][33];
  int bx = blockIdx.x, by = blockIdx.y;
  int x = bx * 32 + threadIdx.x;
#pragma unroll
  for (int i = 0; i < 32; i += 8) {
    int y = by * 32 + threadIdx.y + i;
    tile[threadIdx.y + i][threadIdx.x] = in[(size_t)y * D_ + x];
  }
  __syncthreads();
  int ox = by * 32 + threadIdx.x;
#pragma unroll
  for (int i = 0; i < 32; i += 8) {
    int oy = bx * 32 + threadIdx.y + i;
    out[(size_t)oy * D_ + ox] = f2bf(tile[threadIdx.x][threadIdx.y + i]);
  }
}

__device__ inline void gload_lds16(const void* g, void* l) {
  __builtin_amdgcn_global_load_lds(
      (const __attribute__((address_space(1))) unsigned*)g,
      (__attribute__((address_space(3))) unsigned*)l, 16, 0, 0);
}

#define BM 128
#define BN 128
#define BK 32

// Triple GEMM (bf16 A, proven r14 path) + fused mgp slice (z==3).
//  z in 0..2: C[z] = (A[z] * Bt[z]^T + bias[z]) * os[z]
//  z==2 writes its result TRANSPOSED as vt(B,H,DH,S) bf16.
//  z==3: mgp = mask ? max(bf16(gp), tiny) : 0 (grid-stride; hides under GEMM)
// blockIdx.x XCD-swizzled (256 blocks, 8 XCDs) for L2 locality.
__global__ __launch_bounds__(256) void gemm_bt3(
    const short* __restrict__ A0, const short* __restrict__ A1, const short* __restrict__ A2,
    const short* __restrict__ Bt0, const short* __restrict__ Bt1, const short* __restrict__ Bt2,
    const float* __restrict__ bs0, const float* __restrict__ bs1, const float* __restrict__ bs2,
    void* C0, void* C1, void* C2,
    short* __restrict__ vtout, int vtmode,
    const int* __restrict__ mask, const float* __restrict__ gp,
    short* __restrict__ mgpout, int nmg,
    int M, int N, int K, int f32out, float os0, float os1, float os2) {
  int z = blockIdx.y;
  if (z == 3) {  // fused mask*gp compression, grid-stride
    int i = (blockIdx.x * 256 + threadIdx.x) * 4;
    int stride = gridDim.x * 256 * 4;
    for (; i < nmg; i += stride) {
      int4 m = *(const int4*)(mask + i);
      float4 g = *(const float4*)(gp + i);
      short b0 = f2bf(g.x); if (!b0) b0 = (short)0x0080;
      short b1 = f2bf(g.y); if (!b1) b1 = (short)0x0080;
      short b2 = f2bf(g.z); if (!b2) b2 = (short)0x0080;
      short b3 = f2bf(g.w); if (!b3) b3 = (short)0x0080;
      s16x4 o;
      o.x = m.x ? b0 : 0;
      o.y = m.y ? b1 : 0;
      o.z = m.z ? b2 : 0;
      o.w = m.w ? b3 : 0;
      *(s16x4*)(mgpout + i) = o;
    }
    return;
  }
  const short* A = z == 0 ? A0 : (z == 1 ? A1 : A2);
  const short* Bt = z == 0 ? Bt0 : (z == 1 ? Bt1 : Bt2);
  const float* bias = z == 0 ? bs0 : (z == 1 ? bs1 : bs2);
  void* C = z == 0 ? C0 : (z == 1 ? C1 : C2);
  float oscale = z == 0 ? os0 : (z == 1 ? os1 : os2);

  __shared__ __align__(16) short As[BM * BK];
  __shared__ __align__(16) short Bs[BN * BK];
  int tid = threadIdx.x;
  int lane = tid & 63, wave = tid >> 6;
  int l15 = lane & 15, l4 = lane >> 4;
  int ntn = N / BN;
  int bid = blockIdx.x;
  bid = ((bid & 7) << 5) | (bid >> 3);  // bijective: nwg=256, 256%8==0
  int bm = bid / ntn, bn = bid % ntn;
  int row0 = bm * BM, col0 = bn * BN;
  int wm = (wave >> 1) * 64, wn = (wave & 1) * 64;

  f32x4 acc[4][4] = {};

  for (int k0 = 0; k0 < K; k0 += BK) {
    __syncthreads();
#pragma unroll
    for (int it = 0; it < 2; ++it) {
      int ch = it * 256 + tid;
      int r = ch >> 2, c = (ch & 3) * 8;
      int ldsbase = (it * 256 + wave * 64) * 8;  // elems; HW adds lane*16B
      gload_lds16(A + (size_t)(row0 + r) * K + k0 + c, &As[ldsbase]);
      gload_lds16(Bt + (size_t)(col0 + r) * K + k0 + c, &Bs[ldsbase]);
    }
    __syncthreads();
    s16x8 af[4], bf[4];
#pragma unroll
    for (int mf = 0; mf < 4; ++mf)
      af[mf] = *(const s16x8*)&As[(wm + mf * 16 + l15) * BK + l4 * 8];
#pragma unroll
    for (int nf = 0; nf < 4; ++nf)
      bf[nf] = *(const s16x8*)&Bs[(wn + nf * 16 + l15) * BK + l4 * 8];
#pragma unroll
    for (int mf = 0; mf < 4; ++mf)
#pragma unroll
      for (int nf = 0; nf < 4; ++nf)
        acc[mf][nf] = __builtin_amdgcn_mfma_f32_16x16x32_bf16(af[mf], bf[nf],
                                                              acc[mf][nf], 0, 0, 0);
  }

  if (vtmode && z == 2) {
    // transposed bf16 write: vt[((b*H+h)*DH + dh)*S + s]
    int b = row0 >> 11;                 // S_ = 2048
    int h = (col0 + wn) >> 6;           // col0+wn multiple of 64
    int sbase = (row0 & (S_ - 1)) + wm + l4 * 4;
    short* vtb = vtout + ((size_t)(b * H_ + h) * DH) * S_;
#pragma unroll
    for (int nf = 0; nf < 4; ++nf) {
      int dh = nf * 16 + l15;
      float bv = bias[col0 + wn + dh];
#pragma unroll
      for (int mf = 0; mf < 4; ++mf) {
        uint2 o;
        o.x = cvtpk(acc[mf][nf][0] + bv, acc[mf][nf][1] + bv);
        o.y = cvtpk(acc[mf][nf][2] + bv, acc[mf][nf][3] + bv);
        *(uint2*)&vtb[(size_t)dh * S_ + sbase + mf * 16] = o;
      }
    }
    return;
  }

#pragma unroll
  for (int nf = 0; nf < 4; ++nf) {
    int gcol = col0 + wn + nf * 16 + l15;
    float bv = bias[gcol];
#pragma unroll
    for (int mf = 0; mf < 4; ++mf) {
#pragma unroll
      for (int r = 0; r < 4; ++r) {
        int grow = row0 + wm + mf * 16 + l4 * 4 + r;
        float v = (acc[mf][nf][r] + bv) * oscale;
        if (f32out)
          ((float*)C)[(size_t)grow * N + gcol] = v;
        else
          ((short*)C)[(size_t)grow * N + gcol] = f2bf(v);
      }
    }
  }
}

#define QB 128
#define NB 64
#define NTILES (S_ / NB)
#define M0_SHIFT 12.0f

// Banked 85us attention (byte-identical to r14's).
__global__ __launch_bounds__(256, 3) void attn_fused(const short* __restrict__ Qp,
                                                     const short* __restrict__ Kp,
                                                     const short* __restrict__ VT,
                                                     const short* __restrict__ MGP,
                                                     short* __restrict__ ctx) {
  __shared__ __align__(16) short Ks[2][64 * 64];
  __shared__ __align__(16) short Vs[2][64 * 64];
  __shared__ __align__(16) short Ps[4][32 * 64];  // wave-private P

  int tid = threadIdx.x, lane = tid & 63, wave = tid >> 6;
  int l15 = lane & 15, l4 = lane >> 4;
  int q0 = blockIdx.x * QB;
  int bh = blockIdx.y;
  int b = bh >> 4, h = bh & 15;
  int wq = wave * 32;

  const short* Qbase = Qp + (size_t)b * S_ * D_ + (size_t)h * DH;
  const short* Kbase = Kp + (size_t)b * S_ * D_ + (size_t)h * DH;
  const short* Vbase = VT + (size_t)(b * H_ + h) * DH * S_;  // rows d, stride S_
  const short* Mrow0 = MGP + (size_t)b * S_ * S_ + (size_t)(q0 + wq + l15) * S_ + l4 * 4;
  const short* Mrow1 = Mrow0 + (size_t)16 * S_;

  int i0 = tid, i1 = 256 + tid;
  int r0 = i0 >> 3, c0 = (i0 & 7) ^ (r0 & 7);
  int r1 = i1 >> 3, c1 = (i1 & 7) ^ (r1 & 7);
  int ldsA = wave * 512;
  int ldsB = 2048 + wave * 512;

#define STAGE(kv0, buf)                                                       \
  do {                                                                        \
    gload_lds16(Kbase + (size_t)((kv0) + r0) * D_ + c0 * 8, &Ks[buf][ldsA]);  \
    gload_lds16(Kbase + (size_t)((kv0) + r1) * D_ + c1 * 8, &Ks[buf][ldsB]);  \
    gload_lds16(Vbase + (size_t)r0 * S_ + (kv0) + c0 * 8, &Vs[buf][ldsA]);    \
    gload_lds16(Vbase + (size_t)r1 * S_ + (kv0) + c1 * 8, &Vs[buf][ldsB]);    \
  } while (0)

  s16x8 qf[2][2];
#pragma unroll
  for (int mf = 0; mf < 2; ++mf)
#pragma unroll
    for (int ks = 0; ks < 2; ++ks)
      qf[mf][ks] = *(const s16x8*)(Qbase + (size_t)(q0 + wq + mf * 16 + l15) * D_ +
                                   ks * 32 + l4 * 8);

  float lsum[2] = {0.f, 0.f};
  f32x4 oacc[2][4] = {};

  STAGE(0, 0);

  int q7 = l15 & 7;
  short* Pw = &Ps[wave][0];
  int prow[2] = {l15 * 64, (16 + l15) * 64};

  for (int t = 0; t < NTILES; ++t) {
    int buf = t & 1;
    int kvt = t * NB;

    uint2 g2[2][4];
#pragma unroll
    for (int nf = 0; nf < 4; ++nf) {
      g2[0][nf] = *(const uint2*)(Mrow0 + kvt + nf * 16);
      g2[1][nf] = *(const uint2*)(Mrow1 + kvt + nf * 16);
    }
    __builtin_amdgcn_sched_barrier(0);
    if (t + 1 < NTILES) {
      STAGE((t + 1) * NB, buf ^ 1);
      __builtin_amdgcn_sched_barrier(0);
      asm volatile("s_waitcnt vmcnt(12)" ::: "memory");
    } else {
      __builtin_amdgcn_sched_barrier(0);
      asm volatile("s_waitcnt vmcnt(8)" ::: "memory");
    }
    __builtin_amdgcn_s_barrier();
    __builtin_amdgcn_sched_barrier(0);

    f32x4 sacc[2][4] = {};
    __builtin_amdgcn_s_setprio(1);
#pragma unroll
    for (int nf = 0; nf < 4; ++nf) {
      int R = nf * 16 + l15;
#pragma unroll
      for (int ks = 0; ks < 2; ++ks) {
        s16x8 kf = *(const s16x8*)&Ks[buf][R * 64 + (((ks * 4 + l4) ^ q7) * 8)];
#pragma unroll
        for (int mf = 0; mf < 2; ++mf)
          sacc[mf][nf] = __builtin_amdgcn_mfma_f32_16x16x32_bf16(kf, qf[mf][ks],
                                                                 sacc[mf][nf], 0, 0, 0);
      }
    }
    __builtin_amdgcn_s_setprio(0);

    float ee[2][4][4];
#pragma unroll
    for (int mf = 0; mf < 2; ++mf)
#pragma unroll
      for (int nf = 0; nf < 4; ++nf)
#pragma unroll
        for (int r = 0; r < 4; ++r)
          ee[mf][nf][r] = exp2v(sacc[mf][nf][r] - M0_SHIFT);

    if (t + 1 < NTILES)
      asm volatile("s_waitcnt vmcnt(4)" ::: "memory");
    else
      asm volatile("s_waitcnt vmcnt(0)" ::: "memory");
    __builtin_amdgcn_sched_barrier(0);

#pragma unroll
    for (int mf = 0; mf < 2; ++mf) {
#pragma unroll
      for (int nf = 0; nf < 4; ++nf) {
        float gv0 = bfbits_lo(g2[mf][nf].x), gv1 = bfbits_hi(g2[mf][nf].x);
        float gv2 = bfbits_lo(g2[mf][nf].y), gv3 = bfbits_hi(g2[mf][nf].y);
        float e0 = ee[mf][nf][0], e1 = ee[mf][nf][1];
        float e2 = ee[mf][nf][2], e3 = ee[mf][nf][3];
        lsum[mf] += (gv0 != 0.f) ? e0 : 0.f;
        lsum[mf] += (gv1 != 0.f) ? e1 : 0.f;
        lsum[mf] += (gv2 != 0.f) ? e2 : 0.f;
        lsum[mf] += (gv3 != 0.f) ? e3 : 0.f;
        uint2 wp;
        wp.x = cvtpk(e0 * gv0, e1 * gv1);
        wp.y = cvtpk(e2 * gv2, e3 * gv3);
        int gr = ((nf * 2 + (l4 >> 1)) ^ q7) * 8 + (l4 & 1) * 4;
        *(uint2*)&Pw[prow[mf] + gr] = wp;
      }
    }

    __builtin_amdgcn_s_setprio(1);
#pragma unroll
    for (int ks = 0; ks < 2; ++ks) {
      s16x8 pa[2];
#pragma unroll
      for (int mf = 0; mf < 2; ++mf)
        pa[mf] = *(const s16x8*)&Pw[prow[mf] + (((ks * 4 + l4) ^ q7) * 8)];
#pragma unroll
      for (int df = 0; df < 4; ++df) {
        s16x8 vf = *(const s16x8*)&Vs[buf][(df * 16 + l15) * 64 +
                                           (((ks * 4 + l4) ^ q7) * 8)];
#pragma unroll
        for (int mf = 0; mf < 2; ++mf)
          oacc[mf][df] = __builtin_amdgcn_mfma_f32_16x16x32_bf16(vf, pa[mf],
                                                                 oacc[mf][df], 0, 0, 0);
      }
    }
    __builtin_amdgcn_s_setprio(0);

    asm volatile("s_waitcnt lgkmcnt(0)" ::: "memory");
    __builtin_amdgcn_s_barrier();
  }
#undef STAGE

#pragma unroll
  for (int mf = 0; mf < 2; ++mf) {
    float ls = lsum[mf];
    ls += __shfl_xor(ls, 16);
    ls += __shfl_xor(ls, 32);
    float inv = 1.f / ls;
    short* crow = ctx + ((size_t)(b * S_ + q0 + wq + mf * 16 + l15)) * D_ + h * DH;
#pragma unroll
    for (int df = 0; df < 4; ++df) {
      uint2 o;
      o.x = cvtpk(oacc[mf][df][0] * inv, oacc[mf][df][1] * inv);
      o.y = cvtpk(oacc[mf][df][2] * inv, oacc[mf][df][3] * inv);
      *(uint2*)(crow + df * 16 + l4 * 4) = o;
    }
  }
}

extern "C" void kernel_launch(void* const* d_in, const int* in_sizes, int n_in,
                              void* d_out, int out_size, void* d_ws, size_t ws_size,
                              hipStream_t stream) {
  const float* query = (const float*)d_in[0];
  const float* key_in = (const float*)d_in[1];
  const float* value = (const float*)d_in[2];
  const float* group_prob = (const float*)d_in[3];
  const int* mask = (const int*)d_in[4];
  const float* wq_k = (const float*)d_in[5];
  const float* wq_b = (const float*)d_in[6];
  const float* wk_k = (const float*)d_in[7];
  const float* wk_b = (const float*)d_in[8];
  const float* wv_k = (const float*)d_in[9];
  const float* wv_b = (const float*)d_in[10];
  const float* wo_k = (const float*)d_in[11];
  const float* wo_b = (const float*)d_in[12];
  float* out = (float*)d_out;

  short* ws = (short*)d_ws;
  const size_t NT = (size_t)B_ * S_ * D_;  // 4.19M elems
  short* qbf = ws;
  short* kbf = qbf + NT;
  short* vbf = kbf + NT;
  short* wqt = vbf + NT;
  short* wkt = wqt + (size_t)D_ * D_;
  short* wvt = wkt + (size_t)D_ * D_;
  short* wot = wvt + (size_t)D_ * D_;
  short* qp = wot + (size_t)D_ * D_;
  short* kp = qp + NT;
  short* vt = kp + NT;   // V projection written directly transposed (B,H,DH,S)
  short* ctx = vt + NT;
  short* mgp = ws;       // reuses qbf+kbf (B*S*S == 2*NT); dead after projections

  int nblk = (int)(NT / 4 / 256);
  cvt3_f32_bf16<<<dim3(nblk, 3), 256, 0, stream>>>(query, key_in, value,
                                                   qbf, kbf, vbf, (int)NT);

  dim3 tb(32, 8);
  transpose_cvt4<<<dim3(D_ / 32, D_ / 32, 4), tb, 0, stream>>>(
      wq_k, wk_k, wv_k, wo_k, wqt, wkt, wvt, wot);

  int M = B_ * S_;
  int gblocks = (M / BM) * (D_ / BN);
  int nmg = B_ * S_ * S_;
  const float QSCALE = 0.125f * 1.4426950408889634f;  // 1/sqrt(dh) * log2(e)
  // z=0..2: projections (bf16 A, proven); z=2 writes transposed into vt;
  // z=3: mgp fusion hidden under GEMM compute.
  // NOTE: mgp aliases qbf/kbf, but z=3 only READS mask/gp (external inputs)
  // and WRITES mgp; the GEMM slices READ qbf/kbf... so z=3 racing z=0/1 on the
  // same region would corrupt A mid-read. AVOID: place mgp in dedicated space.
  gemm_bt3<<<dim3(gblocks, 4), 256, 0, stream>>>(
      qbf, kbf, vbf, wqt, wkt, wvt, wq_b, wk_b, wv_b, qp, kp, nullptr,
      vt, 1, mask, group_prob, ctx + NT /* dedicated mgp region */, nmg,
      M, D_, D_, 0, QSCALE, 1.0f, 1.0f);

  dim3 ag(S_ / QB, B_ * H_);
  attn_fused<<<ag, 256, 0, stream>>>(qp, kp, vt, ctx + NT, ctx);

  gemm_bt3<<<dim3(gblocks, 1), 256, 0, stream>>>(
      ctx, ctx, ctx, wot, wot, wot, wo_b, wo_b, wo_b, out, out, out,
      nullptr, 0, nullptr, nullptr, nullptr, 0,
      M, D_, D_, 1, 1.0f, 1.0f, 1.0f);
}

// Round 18
// 174.036 us; speedup vs baseline: 1.0291x; 1.0067x over previous
//
#include <hip/hip_runtime.h>
#include <hip/hip_bf16.h>
#include <stdint.h>

#define B_ 2
#define S_ 2048
#define D_ 1024
#define H_ 16
#define DH 64

typedef __attribute__((ext_vector_type(4))) float f32x4;
typedef __attribute__((ext_vector_type(8))) short s16x8;
typedef __attribute__((ext_vector_type(4))) short s16x4;

__device__ inline short f2bf(float f) {
  union { float f; unsigned u; } v; v.f = f;
  unsigned r = (v.u + 0x7fffu + ((v.u >> 16) & 1u)) >> 16;
  return (short)r;
}

__device__ inline float bfbits_lo(unsigned u) {
  union { unsigned x; float f; } v; v.x = u << 16; return v.f;
}
__device__ inline float bfbits_hi(unsigned u) {
  union { unsigned x; float f; } v; v.x = u & 0xffff0000u; return v.f;
}

__device__ inline float exp2v(float x) {
  float r; asm("v_exp_f32 %0, %1" : "=v"(r) : "v"(x)); return r;
}
__device__ inline unsigned cvtpk(float a, float b) {
  unsigned r; asm("v_cvt_pk_bf16_f32 %0, %1, %2" : "=v"(r) : "v"(a), "v"(b));
  return r;
}

// 3 tensors f32->bf16 in one launch (blockIdx.y selects)
__global__ __launch_bounds__(256) void cvt3_f32_bf16(const float* __restrict__ a,
                                                     const float* __restrict__ b,
                                                     const float* __restrict__ c,
                                                     short* oa, short* ob, short* oc,
                                                     int n) {
  int z = blockIdx.y;
  const float* in = z == 0 ? a : (z == 1 ? b : c);
  short* out = z == 0 ? oa : (z == 1 ? ob : oc);
  int i = (blockIdx.x * 256 + threadIdx.x) * 4;
  if (i < n) {
    float4 v = *(const float4*)(in + i);
    s16x4 o;
    o.x = f2bf(v.x); o.y = f2bf(v.y); o.z = f2bf(v.z); o.w = f2bf(v.w);
    *(s16x4*)(out + i) = o;
  }
}

// 4 weight matrices: out[n][k] = (bf16) in[k][n], D_ x D_ (blockIdx.z selects)
__global__ __launch_bounds__(256) void transpose_cvt4(
    const float* __restrict__ i0, const float* __restrict__ i1,
    const float* __restrict__ i2, const float* __restrict__ i3,
    short* o0, short* o1, short* o2, short* o3) {
  int z = blockIdx.z;
  const float* in = z == 0 ? i0 : (z == 1 ? i1 : (z == 2 ? i2 : i3));
  short* out = z == 0 ? o0 : (z == 1 ? o1 : (z == 2 ? o2 : o3));
  __shared__ float tile[32][33];
  int bx = blockIdx.x, by = blockIdx.y;
  int x = bx * 32 + threadIdx.x;
#pragma unroll
  for (int i = 0; i < 32; i += 8) {
    int y = by * 32 + threadIdx.y + i;
    tile[threadIdx.y + i][threadIdx.x] = in[(size_t)y * D_ + x];
  }
  __syncthreads();
  int ox = by * 32 + threadIdx.x;
#pragma unroll
  for (int i = 0; i < 32; i += 8) {
    int oy = bx * 32 + threadIdx.y + i;
    out[(size_t)oy * D_ + ox] = f2bf(tile[threadIdx.x][threadIdx.y + i]);
  }
}

__device__ inline void gload_lds16(const void* g, void* l) {
  __builtin_amdgcn_global_load_lds(
      (const __attribute__((address_space(1))) unsigned*)g,
      (__attribute__((address_space(3))) unsigned*)l, 16, 0, 0);
}

#define BM 128
#define BN 128
#define BK 32

// Triple GEMM (bf16 A, proven path) + fused mgp slice (z==3).
//  z in 0..2: C[z] = (A[z] * Bt[z]^T + bias[z]) * os[z]
//  z==2 writes its result TRANSPOSED as vt(B,H,DH,S) bf16.
//  z==3: mgp = mask ? max(bf16(gp), tiny) : 0 (grid-stride; hides under GEMM)
// blockIdx.x XCD-swizzled (256 blocks, 8 XCDs) for L2 locality.
__global__ __launch_bounds__(256) void gemm_bt3(
    const short* __restrict__ A0, const short* __restrict__ A1, const short* __restrict__ A2,
    const short* __restrict__ Bt0, const short* __restrict__ Bt1, const short* __restrict__ Bt2,
    const float* __restrict__ bs0, const float* __restrict__ bs1, const float* __restrict__ bs2,
    void* C0, void* C1, void* C2,
    short* __restrict__ vtout, int vtmode,
    const int* __restrict__ mask, const float* __restrict__ gp,
    short* __restrict__ mgpout, int nmg,
    int M, int N, int K, int f32out, float os0, float os1, float os2) {
  int z = blockIdx.y;
  if (z == 3) {  // fused mask*gp compression, grid-stride
    int i = (blockIdx.x * 256 + threadIdx.x) * 4;
    int stride = gridDim.x * 256 * 4;
    for (; i < nmg; i += stride) {
      int4 m = *(const int4*)(mask + i);
      float4 g = *(const float4*)(gp + i);
      short b0 = f2bf(g.x); if (!b0) b0 = (short)0x0080;
      short b1 = f2bf(g.y); if (!b1) b1 = (short)0x0080;
      short b2 = f2bf(g.z); if (!b2) b2 = (short)0x0080;
      short b3 = f2bf(g.w); if (!b3) b3 = (short)0x0080;
      s16x4 o;
      o.x = m.x ? b0 : 0;
      o.y = m.y ? b1 : 0;
      o.z = m.z ? b2 : 0;
      o.w = m.w ? b3 : 0;
      *(s16x4*)(mgpout + i) = o;
    }
    return;
  }
  const short* A = z == 0 ? A0 : (z == 1 ? A1 : A2);
  const short* Bt = z == 0 ? Bt0 : (z == 1 ? Bt1 : Bt2);
  const float* bias = z == 0 ? bs0 : (z == 1 ? bs1 : bs2);
  void* C = z == 0 ? C0 : (z == 1 ? C1 : C2);
  float oscale = z == 0 ? os0 : (z == 1 ? os1 : os2);

  __shared__ __align__(16) short As[BM * BK];
  __shared__ __align__(16) short Bs[BN * BK];
  int tid = threadIdx.x;
  int lane = tid & 63, wave = tid >> 6;
  int l15 = lane & 15, l4 = lane >> 4;
  int ntn = N / BN;
  int bid = blockIdx.x;
  bid = ((bid & 7) << 5) | (bid >> 3);  // bijective: nwg=256, 256%8==0
  int bm = bid / ntn, bn = bid % ntn;
  int row0 = bm * BM, col0 = bn * BN;
  int wm = (wave >> 1) * 64, wn = (wave & 1) * 64;

  f32x4 acc[4][4] = {};

  for (int k0 = 0; k0 < K; k0 += BK) {
    __syncthreads();
#pragma unroll
    for (int it = 0; it < 2; ++it) {
      int ch = it * 256 + tid;
      int r = ch >> 2, c = (ch & 3) * 8;
      int ldsbase = (it * 256 + wave * 64) * 8;  // elems; HW adds lane*16B
      gload_lds16(A + (size_t)(row0 + r) * K + k0 + c, &As[ldsbase]);
      gload_lds16(Bt + (size_t)(col0 + r) * K + k0 + c, &Bs[ldsbase]);
    }
    __syncthreads();
    s16x8 af[4], bf[4];
#pragma unroll
    for (int mf = 0; mf < 4; ++mf)
      af[mf] = *(const s16x8*)&As[(wm + mf * 16 + l15) * BK + l4 * 8];
#pragma unroll
    for (int nf = 0; nf < 4; ++nf)
      bf[nf] = *(const s16x8*)&Bs[(wn + nf * 16 + l15) * BK + l4 * 8];
#pragma unroll
    for (int mf = 0; mf < 4; ++mf)
#pragma unroll
      for (int nf = 0; nf < 4; ++nf)
        acc[mf][nf] = __builtin_amdgcn_mfma_f32_16x16x32_bf16(af[mf], bf[nf],
                                                              acc[mf][nf], 0, 0, 0);
  }

  if (vtmode && z == 2) {
    // transposed bf16 write: vt[((b*H+h)*DH + dh)*S + s]
    int b = row0 >> 11;                 // S_ = 2048
    int h = (col0 + wn) >> 6;           // col0+wn multiple of 64
    int sbase = (row0 & (S_ - 1)) + wm + l4 * 4;
    short* vtb = vtout + ((size_t)(b * H_ + h) * DH) * S_;
#pragma unroll
    for (int nf = 0; nf < 4; ++nf) {
      int dh = nf * 16 + l15;
      float bv = bias[col0 + wn + dh];
#pragma unroll
      for (int mf = 0; mf < 4; ++mf) {
        uint2 o;
        o.x = cvtpk(acc[mf][nf][0] + bv, acc[mf][nf][1] + bv);
        o.y = cvtpk(acc[mf][nf][2] + bv, acc[mf][nf][3] + bv);
        *(uint2*)&vtb[(size_t)dh * S_ + sbase + mf * 16] = o;
      }
    }
    return;
  }

#pragma unroll
  for (int nf = 0; nf < 4; ++nf) {
    int gcol = col0 + wn + nf * 16 + l15;
    float bv = bias[gcol];
#pragma unroll
    for (int mf = 0; mf < 4; ++mf) {
#pragma unroll
      for (int r = 0; r < 4; ++r) {
        int grow = row0 + wm + mf * 16 + l4 * 4 + r;
        float v = (acc[mf][nf][r] + bv) * oscale;
        if (f32out)
          ((float*)C)[(size_t)grow * N + gcol] = v;
        else
          ((short*)C)[(size_t)grow * N + gcol] = f2bf(v);
      }
    }
  }
}

#define QB 128
#define NB 64
#define NTILES (S_ / NB)
#define M0_SHIFT 12.0f

// Banked attn structure + ONE delta: K/V triple-buffered, bottom barrier
// removed (one barrier per tile). Safety: top barrier keeps waves within 1
// iteration; STAGE(t+2) writes buf (t+2)%3 which never collides with
// readers of buf t%3; lgkmcnt(0) folded into the top wait orders each
// wave's own ds_reads. vmcnt counts unchanged (same per-tile issue pattern).
__global__ __launch_bounds__(256, 2) void attn_fused(const short* __restrict__ Qp,
                                                     const short* __restrict__ Kp,
                                                     const short* __restrict__ VT,
                                                     const short* __restrict__ MGP,
                                                     short* __restrict__ ctx) {
  __shared__ __align__(16) short Ks[3][64 * 64];
  __shared__ __align__(16) short Vs[3][64 * 64];
  __shared__ __align__(16) short Ps[4][32 * 64];  // wave-private P

  int tid = threadIdx.x, lane = tid & 63, wave = tid >> 6;
  int l15 = lane & 15, l4 = lane >> 4;
  int q0 = blockIdx.x * QB;
  int bh = blockIdx.y;
  int b = bh >> 4, h = bh & 15;
  int wq = wave * 32;

  const short* Qbase = Qp + (size_t)b * S_ * D_ + (size_t)h * DH;
  const short* Kbase = Kp + (size_t)b * S_ * D_ + (size_t)h * DH;
  const short* Vbase = VT + (size_t)(b * H_ + h) * DH * S_;  // rows d, stride S_
  const short* Mrow0 = MGP + (size_t)b * S_ * S_ + (size_t)(q0 + wq + l15) * S_ + l4 * 4;
  const short* Mrow1 = Mrow0 + (size_t)16 * S_;

  int i0 = tid, i1 = 256 + tid;
  int r0 = i0 >> 3, c0 = (i0 & 7) ^ (r0 & 7);
  int r1 = i1 >> 3, c1 = (i1 & 7) ^ (r1 & 7);
  int ldsA = wave * 512;
  int ldsB = 2048 + wave * 512;

#define STAGE(kv0, buf)                                                       \
  do {                                                                        \
    gload_lds16(Kbase + (size_t)((kv0) + r0) * D_ + c0 * 8, &Ks[buf][ldsA]);  \
    gload_lds16(Kbase + (size_t)((kv0) + r1) * D_ + c1 * 8, &Ks[buf][ldsB]);  \
    gload_lds16(Vbase + (size_t)r0 * S_ + (kv0) + c0 * 8, &Vs[buf][ldsA]);    \
    gload_lds16(Vbase + (size_t)r1 * S_ + (kv0) + c1 * 8, &Vs[buf][ldsB]);    \
  } while (0)

  s16x8 qf[2][2];
#pragma unroll
  for (int mf = 0; mf < 2; ++mf)
#pragma unroll
    for (int ks = 0; ks < 2; ++ks)
      qf[mf][ks] = *(const s16x8*)(Qbase + (size_t)(q0 + wq + mf * 16 + l15) * D_ +
                                   ks * 32 + l4 * 8);

  float lsum[2] = {0.f, 0.f};
  f32x4 oacc[2][4] = {};

  STAGE(0, 0);

  int q7 = l15 & 7;
  short* Pw = &Ps[wave][0];
  int prow[2] = {l15 * 64, (16 + l15) * 64};

  int buf = 0;
  for (int t = 0; t < NTILES; ++t) {
    int kvt = t * NB;
    int nxt = buf + 1; if (nxt == 3) nxt = 0;

    // early mgp loads (global->reg); pinned before STAGE by sched_barrier
    uint2 g2[2][4];
#pragma unroll
    for (int nf = 0; nf < 4; ++nf) {
      g2[0][nf] = *(const uint2*)(Mrow0 + kvt + nf * 16);
      g2[1][nf] = *(const uint2*)(Mrow1 + kvt + nf * 16);
    }
    __builtin_amdgcn_sched_barrier(0);
    if (t + 1 < NTILES) {
      STAGE((t + 1) * NB, nxt);
      __builtin_amdgcn_sched_barrier(0);
      // outstanding: 4 (tile-t stage, oldest) + 8 mgp + 4 (t+1 stage)
      asm volatile("s_waitcnt vmcnt(12) lgkmcnt(0)" ::: "memory");
    } else {
      __builtin_amdgcn_sched_barrier(0);
      asm volatile("s_waitcnt vmcnt(8) lgkmcnt(0)" ::: "memory");
    }
    __builtin_amdgcn_s_barrier();
    __builtin_amdgcn_sched_barrier(0);

    // QK^T swapped: sacc[mf][nf] = S^T[kv = nf*16 + l4*4 + r][q = wq+mf*16+l15]
    f32x4 sacc[2][4] = {};
    __builtin_amdgcn_s_setprio(1);
#pragma unroll
    for (int nf = 0; nf < 4; ++nf) {
      int R = nf * 16 + l15;
#pragma unroll
      for (int ks = 0; ks < 2; ++ks) {
        s16x8 kf = *(const s16x8*)&Ks[buf][R * 64 + (((ks * 4 + l4) ^ q7) * 8)];
#pragma unroll
        for (int mf = 0; mf < 2; ++mf)
          sacc[mf][nf] = __builtin_amdgcn_mfma_f32_16x16x32_bf16(kf, qf[mf][ks],
                                                                 sacc[mf][nf], 0, 0, 0);
      }
    }
    __builtin_amdgcn_s_setprio(0);

    // exp pass — depends only on sacc, runs while mgp loads land
    float ee[2][4][4];
#pragma unroll
    for (int mf = 0; mf < 2; ++mf)
#pragma unroll
      for (int nf = 0; nf < 4; ++nf)
#pragma unroll
        for (int r = 0; r < 4; ++r)
          ee[mf][nf][r] = exp2v(sacc[mf][nf][r] - M0_SHIFT);

    // mgp regs arrived (next-tile staging stays in flight)
    if (t + 1 < NTILES)
      asm volatile("s_waitcnt vmcnt(4)" ::: "memory");
    else
      asm volatile("s_waitcnt vmcnt(0)" ::: "memory");
    __builtin_amdgcn_sched_barrier(0);

    // gv pass: mask/weight, lsum accumulate, P*gp into wave-private Ps
#pragma unroll
    for (int mf = 0; mf < 2; ++mf) {
#pragma unroll
      for (int nf = 0; nf < 4; ++nf) {
        float gv0 = bfbits_lo(g2[mf][nf].x), gv1 = bfbits_hi(g2[mf][nf].x);
        float gv2 = bfbits_lo(g2[mf][nf].y), gv3 = bfbits_hi(g2[mf][nf].y);
        float e0 = ee[mf][nf][0], e1 = ee[mf][nf][1];
        float e2 = ee[mf][nf][2], e3 = ee[mf][nf][3];
        lsum[mf] += (gv0 != 0.f) ? e0 : 0.f;
        lsum[mf] += (gv1 != 0.f) ? e1 : 0.f;
        lsum[mf] += (gv2 != 0.f) ? e2 : 0.f;
        lsum[mf] += (gv3 != 0.f) ? e3 : 0.f;
        uint2 wp;
        wp.x = cvtpk(e0 * gv0, e1 * gv1);
        wp.y = cvtpk(e2 * gv2, e3 * gv3);
        // granule swizzle: phys granule = logical granule ^ (row&7)
        int gr = ((nf * 2 + (l4 >> 1)) ^ q7) * 8 + (l4 & 1) * 4;
        *(uint2*)&Pw[prow[mf] + gr] = wp;
      }
    }

    // PV swapped: oacc[mf][df] = O^T[d = df*16 + l4*4 + r][q = wq+mf*16+l15]
    __builtin_amdgcn_s_setprio(1);
#pragma unroll
    for (int ks = 0; ks < 2; ++ks) {
      s16x8 pa[2];
#pragma unroll
      for (int mf = 0; mf < 2; ++mf)
        pa[mf] = *(const s16x8*)&Pw[prow[mf] + (((ks * 4 + l4) ^ q7) * 8)];
#pragma unroll
      for (int df = 0; df < 4; ++df) {
        s16x8 vf = *(const s16x8*)&Vs[buf][(df * 16 + l15) * 64 +
                                           (((ks * 4 + l4) ^ q7) * 8)];
#pragma unroll
        for (int mf = 0; mf < 2; ++mf)
          oacc[mf][df] = __builtin_amdgcn_mfma_f32_16x16x32_bf16(vf, pa[mf],
                                                                 oacc[mf][df], 0, 0, 0);
      }
    }
    __builtin_amdgcn_s_setprio(0);

    buf = nxt;  // no bottom barrier: 3 buffers + top barrier make it safe
  }
#undef STAGE

  // epilogue: denominator reduce across the 4 l4 groups, store O^T/l
#pragma unroll
  for (int mf = 0; mf < 2; ++mf) {
    float ls = lsum[mf];
    ls += __shfl_xor(ls, 16);
    ls += __shfl_xor(ls, 32);
    float inv = 1.f / ls;
    short* crow = ctx + ((size_t)(b * S_ + q0 + wq + mf * 16 + l15)) * D_ + h * DH;
#pragma unroll
    for (int df = 0; df < 4; ++df) {
      uint2 o;
      o.x = cvtpk(oacc[mf][df][0] * inv, oacc[mf][df][1] * inv);
      o.y = cvtpk(oacc[mf][df][2] * inv, oacc[mf][df][3] * inv);
      *(uint2*)(crow + df * 16 + l4 * 4) = o;
    }
  }
}

extern "C" void kernel_launch(void* const* d_in, const int* in_sizes, int n_in,
                              void* d_out, int out_size, void* d_ws, size_t ws_size,
                              hipStream_t stream) {
  const float* query = (const float*)d_in[0];
  const float* key_in = (const float*)d_in[1];
  const float* value = (const float*)d_in[2];
  const float* group_prob = (const float*)d_in[3];
  const int* mask = (const int*)d_in[4];
  const float* wq_k = (const float*)d_in[5];
  const float* wq_b = (const float*)d_in[6];
  const float* wk_k = (const float*)d_in[7];
  const float* wk_b = (const float*)d_in[8];
  const float* wv_k = (const float*)d_in[9];
  const float* wv_b = (const float*)d_in[10];
  const float* wo_k = (const float*)d_in[11];
  const float* wo_b = (const float*)d_in[12];
  float* out = (float*)d_out;

  short* ws = (short*)d_ws;
  const size_t NT = (size_t)B_ * S_ * D_;  // 4.19M elems
  short* qbf = ws;
  short* kbf = qbf + NT;
  short* vbf = kbf + NT;
  short* wqt = vbf + NT;
  short* wkt = wqt + (size_t)D_ * D_;
  short* wvt = wkt + (size_t)D_ * D_;
  short* wot = wvt + (size_t)D_ * D_;
  short* qp = wot + (size_t)D_ * D_;
  short* kp = qp + NT;
  short* vt = kp + NT;   // V projection written directly transposed (B,H,DH,S)
  short* ctx = vt + NT;
  short* mgp = ctx + NT; // dedicated region (z=3 writes while z=0..2 read qbf/kbf)

  int nblk = (int)(NT / 4 / 256);
  cvt3_f32_bf16<<<dim3(nblk, 3), 256, 0, stream>>>(query, key_in, value,
                                                   qbf, kbf, vbf, (int)NT);

  dim3 tb(32, 8);
  transpose_cvt4<<<dim3(D_ / 32, D_ / 32, 4), tb, 0, stream>>>(
      wq_k, wk_k, wv_k, wo_k, wqt, wkt, wvt, wot);

  int M = B_ * S_;
  int gblocks = (M / BM) * (D_ / BN);
  int nmg = B_ * S_ * S_;
  const float QSCALE = 0.125f * 1.4426950408889634f;  // 1/sqrt(dh) * log2(e)
  // z=0..2: projections (bf16 A, proven); z=2 writes transposed into vt;
  // z=3: mgp fusion hidden under GEMM compute (dedicated mgp region).
  gemm_bt3<<<dim3(gblocks, 4), 256, 0, stream>>>(
      qbf, kbf, vbf, wqt, wkt, wvt, wq_b, wk_b, wv_b, qp, kp, nullptr,
      vt, 1, mask, group_prob, mgp, nmg,
      M, D_, D_, 0, QSCALE, 1.0f, 1.0f);

  dim3 ag(S_ / QB, B_ * H_);
  attn_fused<<<ag, 256, 0, stream>>>(qp, kp, vt, mgp, ctx);

  gemm_bt3<<<dim3(gblocks, 1), 256, 0, stream>>>(
      ctx, ctx, ctx, wot, wot, wot, wo_b, wo_b, wo_b, out, out, out,
      nullptr, 0, nullptr, nullptr, nullptr, 0,
      M, D_, D_, 1, 1.0f, 1.0f, 1.0f);
}